// Round 1
// baseline (8128.883 us; speedup 1.0000x reference)
//
#include <hip/hip_runtime.h>
#include <math.h>

#define TSTEPS 63
#define BB 64
#define ED 512
#define HD 1024
#define VV 32000
#define GG 4096            // 4*HD
#define NROWS 4032         // TSTEPS*BB
#define NCHUNK 50
#define CHW 640            // vocab cols per chunk (10 subtiles of 64)
#define PSTRIDE 262144     // BB*GG

__device__ __forceinline__ float sigf(float x) { return 1.0f / (1.0f + __expf(-x)); }

// ---------------- state init ----------------
__global__ __launch_bounds__(256)
void init_state_k(const float* __restrict__ h0, const float* __restrict__ c0,
                  float* __restrict__ hs, float* __restrict__ cs) {
  int i = blockIdx.x * 256 + threadIdx.x;
  hs[i] = h0[i];
  cs[i] = c0[i];
}

// ---------------- X0 = gather(emb) @ Wih0^T + bih0 + bhh0 ----------------
// grid (63, 64): t x ntile ; 256 thr; 64x64 tile, K=512
__global__ __launch_bounds__(256)
void x0_gemm_k(const int* __restrict__ dec, const float* __restrict__ emb,
               const float* __restrict__ Wih0, const float* __restrict__ bih0,
               const float* __restrict__ bhh0, float* __restrict__ X0) {
  __shared__ float As[16][68];
  __shared__ float Bs[16][68];
  int t  = blockIdx.x;
  int n0 = blockIdx.y * 64;
  int tid = threadIdx.x;
  int tx = tid & 15, ty = tid >> 4;
  int lm = tid >> 2, lk = (tid & 3) * 4;
  int rowid = dec[t * 64 + lm];           // gather index for A-load row
  float acc[4][4] = {};
  for (int k0 = 0; k0 < ED; k0 += 16) {
    float4 av = *(const float4*)(emb  + (size_t)rowid * ED + k0 + lk);
    float4 bv = *(const float4*)(Wih0 + (size_t)(n0 + lm) * ED + k0 + lk);
    As[lk + 0][lm] = av.x; As[lk + 1][lm] = av.y; As[lk + 2][lm] = av.z; As[lk + 3][lm] = av.w;
    Bs[lk + 0][lm] = bv.x; Bs[lk + 1][lm] = bv.y; Bs[lk + 2][lm] = bv.z; Bs[lk + 3][lm] = bv.w;
    __syncthreads();
#pragma unroll
    for (int kk = 0; kk < 16; kk++) {
      float a4[4], b4[4];
      *(float4*)a4 = *(const float4*)&As[kk][ty * 4];
      *(float4*)b4 = *(const float4*)&Bs[kk][tx * 4];
#pragma unroll
      for (int i = 0; i < 4; i++)
#pragma unroll
        for (int j = 0; j < 4; j++) acc[i][j] += a4[i] * b4[j];
    }
    __syncthreads();
  }
  size_t rbase = (size_t)t * 64;
#pragma unroll
  for (int i = 0; i < 4; i++) {
    int b = ty * 4 + i;
#pragma unroll
    for (int j = 0; j < 4; j++) {
      int n = n0 + tx * 4 + j;
      X0[(rbase + b) * GG + n] = acc[i][j] + bih0[n] + bhh0[n];
    }
  }
}

// ---------------- recurrent partial GEMM ----------------
// part[p][b][n] = sum_{k in chunk} A[b][k] * W[n][k]
// grid (64, P): ntile x K-chunk ; p<4 uses (A0,W0), p>=4 uses (A1,W1)
__global__ __launch_bounds__(256)
void rec_gemm_k(const float* __restrict__ A0, const float* __restrict__ W0,
                const float* __restrict__ A1, const float* __restrict__ W1,
                float* __restrict__ part) {
  __shared__ float As[16][68];
  __shared__ float Bs[16][68];
  int n0 = blockIdx.x * 64;
  int p  = blockIdx.y;
  const float* A = (p < 4) ? A0 : A1;
  const float* W = (p < 4) ? W0 : W1;
  int koff = (p & 3) * 256;
  int tid = threadIdx.x;
  int tx = tid & 15, ty = tid >> 4;
  int lm = tid >> 2, lk = (tid & 3) * 4;
  float acc[4][4] = {};
  for (int k0 = koff; k0 < koff + 256; k0 += 16) {
    float4 av = *(const float4*)(A + (size_t)lm * HD + k0 + lk);
    float4 bv = *(const float4*)(W + (size_t)(n0 + lm) * HD + k0 + lk);
    As[lk + 0][lm] = av.x; As[lk + 1][lm] = av.y; As[lk + 2][lm] = av.z; As[lk + 3][lm] = av.w;
    Bs[lk + 0][lm] = bv.x; Bs[lk + 1][lm] = bv.y; Bs[lk + 2][lm] = bv.z; Bs[lk + 3][lm] = bv.w;
    __syncthreads();
#pragma unroll
    for (int kk = 0; kk < 16; kk++) {
      float a4[4], b4[4];
      *(float4*)a4 = *(const float4*)&As[kk][ty * 4];
      *(float4*)b4 = *(const float4*)&Bs[kk][tx * 4];
#pragma unroll
      for (int i = 0; i < 4; i++)
#pragma unroll
        for (int j = 0; j < 4; j++) acc[i][j] += a4[i] * b4[j];
    }
    __syncthreads();
  }
  float* dst = part + (size_t)p * PSTRIDE;
#pragma unroll
  for (int i = 0; i < 4; i++)
#pragma unroll
    for (int j = 0; j < 4; j++)
      dst[(size_t)(ty * 4 + i) * GG + n0 + tx * 4 + j] = acc[i][j];
}

// ---------------- LSTM cell, layer 0 (X0 already has both biases) ----------------
__global__ __launch_bounds__(256)
void cell0_k(const float* __restrict__ X0t, const float* __restrict__ part,
             float* __restrict__ h, float* __restrict__ c) {
  int idx = blockIdx.x * 256 + threadIdx.x;  // 0..65535
  int b = idx >> 10, j = idx & (HD - 1);
  float g[4];
#pragma unroll
  for (int q = 0; q < 4; q++) {
    size_t o = (size_t)b * GG + q * HD + j;
    g[q] = X0t[o] + part[o] + part[o + PSTRIDE] + part[o + 2 * PSTRIDE] + part[o + 3 * PSTRIDE];
  }
  float cn = sigf(g[1]) * c[idx] + sigf(g[0]) * tanhf(g[2]);
  float hn = sigf(g[3]) * tanhf(cn);
  c[idx] = cn;
  h[idx] = hn;
}

// ---------------- LSTM cell, layer 1 (adds biases, writes H1) ----------------
__global__ __launch_bounds__(256)
void cell1_k(const float* __restrict__ part, const float* __restrict__ bih,
             const float* __restrict__ bhh, float* __restrict__ h,
             float* __restrict__ c, float* __restrict__ H1t) {
  int idx = blockIdx.x * 256 + threadIdx.x;
  int b = idx >> 10, j = idx & (HD - 1);
  float g[4];
#pragma unroll
  for (int q = 0; q < 4; q++) {
    int gi = q * HD + j;
    size_t o = (size_t)b * GG + gi;
    float v = bih[gi] + bhh[gi];
#pragma unroll
    for (int p = 0; p < 8; p++) v += part[(size_t)p * PSTRIDE + o];
    g[q] = v;
  }
  float cn = sigf(g[1]) * c[idx] + sigf(g[0]) * tanhf(g[2]);
  float hn = sigf(g[3]) * tanhf(cn);
  c[idx] = cn;
  h[idx] = hn;
  H1t[idx] = hn;
}

// ---------------- target logit: tl[r] = dot(H1[r], Wout[tgt[r]]) + bout[tgt[r]] ----------------
__global__ __launch_bounds__(256)
void tgt_logit_k(const float* __restrict__ H1, const float* __restrict__ Wout,
                 const float* __restrict__ bout, const int* __restrict__ dec,
                 float* __restrict__ tl) {
  int gw = (blockIdx.x * 256 + threadIdx.x) >> 6;  // global wave id = row
  int lane = threadIdx.x & 63;
  if (gw >= NROWS) return;
  int tgt = dec[gw + 64];  // dec_input[1:]
  const float* hrow = H1 + (size_t)gw * HD;
  const float* wrow = Wout + (size_t)tgt * HD;
  float s = 0.f;
#pragma unroll
  for (int q = 0; q < 16; q++) {
    int k = lane + q * 64;
    s += hrow[k] * wrow[k];
  }
#pragma unroll
  for (int off = 32; off > 0; off >>= 1) s += __shfl_down(s, off);
  if (lane == 0) tl[gw] = s + bout[tgt];
}

// ---------------- fused logits GEMM + online LSE partials ----------------
// grid (16, 50): rowgroup x vocab-chunk. Each block: rowtiles rt=rb,rb+16,.. (64 rows),
// 10 subtiles of 64 cols each, K=1024.  Writes m_part/s_part[row][chunk].
__global__ __launch_bounds__(256)
void lse_partial_k(const float* __restrict__ H1, const float* __restrict__ Wout,
                   const float* __restrict__ bout, float* __restrict__ m_part,
                   float* __restrict__ s_part) {
  __shared__ float As[16][68];
  __shared__ float Bs[16][68];
  int ch = blockIdx.y;
  int tid = threadIdx.x;
  int tx = tid & 15, ty = tid >> 4;
  int lm = tid >> 2, lk = (tid & 3) * 4;
  for (int rt = blockIdx.x; rt < TSTEPS; rt += 16) {
    const float* Arows = H1 + (size_t)rt * 64 * HD;
    float mrun[4], srun[4];
#pragma unroll
    for (int i = 0; i < 4; i++) { mrun[i] = -INFINITY; srun[i] = 0.f; }
    for (int sub = 0; sub < 10; sub++) {
      int n0 = ch * CHW + sub * 64;
      float acc[4][4] = {};
      for (int k0 = 0; k0 < HD; k0 += 16) {
        float4 av = *(const float4*)(Arows + (size_t)lm * HD + k0 + lk);
        float4 bv = *(const float4*)(Wout + (size_t)(n0 + lm) * HD + k0 + lk);
        As[lk + 0][lm] = av.x; As[lk + 1][lm] = av.y; As[lk + 2][lm] = av.z; As[lk + 3][lm] = av.w;
        Bs[lk + 0][lm] = bv.x; Bs[lk + 1][lm] = bv.y; Bs[lk + 2][lm] = bv.z; Bs[lk + 3][lm] = bv.w;
        __syncthreads();
#pragma unroll
        for (int kk = 0; kk < 16; kk++) {
          float a4[4], b4[4];
          *(float4*)a4 = *(const float4*)&As[kk][ty * 4];
          *(float4*)b4 = *(const float4*)&Bs[kk][tx * 4];
#pragma unroll
          for (int i = 0; i < 4; i++)
#pragma unroll
            for (int j = 0; j < 4; j++) acc[i][j] += a4[i] * b4[j];
        }
        __syncthreads();
      }
      float bo[4];
      *(float4*)bo = *(const float4*)(bout + n0 + tx * 4);
#pragma unroll
      for (int i = 0; i < 4; i++) {
#pragma unroll
        for (int j = 0; j < 4; j++) {
          float v = acc[i][j] + bo[j];
          float mn = fmaxf(mrun[i], v);
          srun[i] = srun[i] * __expf(mrun[i] - mn) + __expf(v - mn);
          mrun[i] = mn;
        }
      }
    }
    // merge (m,s) across the 16 tx lanes sharing each row (contiguous 16-lane groups)
#pragma unroll
    for (int i = 0; i < 4; i++) {
#pragma unroll
      for (int off = 1; off < 16; off <<= 1) {
        float mo = __shfl_xor(mrun[i], off);
        float so = __shfl_xor(srun[i], off);
        float mn = fmaxf(mrun[i], mo);
        srun[i] = srun[i] * __expf(mrun[i] - mn) + so * __expf(mo - mn);
        mrun[i] = mn;
      }
    }
    if (tx == 0) {
#pragma unroll
      for (int i = 0; i < 4; i++) {
        int row = rt * 64 + ty * 4 + i;
        m_part[(size_t)row * NCHUNK + ch] = mrun[i];
        s_part[(size_t)row * NCHUNK + ch] = srun[i];
      }
    }
  }
}

// ---------------- final loss reduce ----------------
__global__ __launch_bounds__(256)
void loss_reduce_k(const float* __restrict__ m_part, const float* __restrict__ s_part,
                   const float* __restrict__ tl, float* __restrict__ out) {
  int tid = threadIdx.x;
  float local = 0.f;
  for (int r = tid; r < NROWS; r += 256) {
    float M = -INFINITY;
    for (int c = 0; c < NCHUNK; c++) M = fmaxf(M, m_part[(size_t)r * NCHUNK + c]);
    float S = 0.f;
    for (int c = 0; c < NCHUNK; c++)
      S += s_part[(size_t)r * NCHUNK + c] * __expf(m_part[(size_t)r * NCHUNK + c] - M);
    local += logf(S) + M - tl[r];
  }
  __shared__ float red[256];
  red[tid] = local;
  __syncthreads();
  for (int s = 128; s > 0; s >>= 1) {
    if (tid < s) red[tid] += red[tid + s];
    __syncthreads();
  }
  if (tid == 0) out[0] = red[0];
}

extern "C" void kernel_launch(void* const* d_in, const int* in_sizes, int n_in,
                              void* d_out, int out_size, void* d_ws, size_t ws_size,
                              hipStream_t stream) {
  const int*   dec  = (const int*)  d_in[0];
  // d_in[1] enc_outputs: unused by the reference
  const float* h0   = (const float*)d_in[2];
  const float* c0   = (const float*)d_in[3];
  const float* emb  = (const float*)d_in[4];
  const float* Wih0 = (const float*)d_in[5];
  const float* Whh0 = (const float*)d_in[6];
  const float* bih0 = (const float*)d_in[7];
  const float* bhh0 = (const float*)d_in[8];
  const float* Wih1 = (const float*)d_in[9];
  const float* Whh1 = (const float*)d_in[10];
  const float* bih1 = (const float*)d_in[11];
  const float* bhh1 = (const float*)d_in[12];
  const float* Wout = (const float*)d_in[13];
  const float* bout = (const float*)d_in[14];
  float* out = (float*)d_out;

  float* ws = (float*)d_ws;
  float* X0     = ws;                                   // 4032*4096   = 16,515,072 f
  float* H1     = X0 + (size_t)NROWS * GG;              // 4032*1024   =  4,128,768 f
  float* hs     = H1 + (size_t)NROWS * HD;              // 2*64*1024
  float* cs     = hs + 2 * BB * HD;                     // 2*64*1024
  float* part   = cs + 2 * BB * HD;                     // 8*64*4096   =  2,097,152 f
  float* m_part = part + 8 * (size_t)BB * GG;           // 4032*50
  float* s_part = m_part + (size_t)NROWS * NCHUNK;      // 4032*50
  float* tl     = s_part + (size_t)NROWS * NCHUNK;      // 4032
  // total ~ 89.3 MiB of d_ws

  float* hs0 = hs, * hs1 = hs + BB * HD;
  float* cs0 = cs, * cs1 = cs + BB * HD;

  init_state_k<<<(2 * BB * HD) / 256, 256, 0, stream>>>(h0, c0, hs, cs);
  x0_gemm_k<<<dim3(TSTEPS, GG / 64), 256, 0, stream>>>(dec, emb, Wih0, bih0, bhh0, X0);

  for (int t = 0; t < TSTEPS; t++) {
    rec_gemm_k<<<dim3(64, 4), 256, 0, stream>>>(hs0, Whh0, hs0, Whh0, part);
    cell0_k<<<256, 256, 0, stream>>>(X0 + (size_t)t * BB * GG, part, hs0, cs0);
    rec_gemm_k<<<dim3(64, 8), 256, 0, stream>>>(hs0, Wih1, hs1, Whh1, part);
    cell1_k<<<256, 256, 0, stream>>>(part, bih1, bhh1, hs1, cs1, H1 + (size_t)t * BB * HD);
  }

  tgt_logit_k<<<(NROWS * 64 + 255) / 256, 256, 0, stream>>>(H1, Wout, bout, dec, tl);
  lse_partial_k<<<dim3(16, NCHUNK), 256, 0, stream>>>(H1, Wout, bout, m_part, s_part);
  loss_reduce_k<<<1, 256, 0, stream>>>(m_part, s_part, tl, out);
}

// Round 2
// 3319.025 us; speedup vs baseline: 2.4492x; 2.4492x over previous
//
#include <hip/hip_runtime.h>
#include <math.h>

#define TSTEPS 63
#define BB 64
#define ED 512
#define HD 1024
#define VV 32000
#define GG 4096            // 4*HD
#define NROWS 4032         // TSTEPS*BB
#define MPAD 4096          // padded row count for MFMA tiles
#define NCH 500            // 64-col LSE chunks (32000/64)
#define PSTRIDE 262144     // BB*GG

typedef __attribute__((ext_vector_type(8))) short short8;
typedef __attribute__((ext_vector_type(4))) float f32x4;

__device__ __forceinline__ float sigf(float x) { return 1.0f / (1.0f + __expf(-x)); }

__device__ __forceinline__ short f2bf(float f) {
  unsigned u = __float_as_uint(f);
  unsigned r = (u + 0x7FFFu + ((u >> 16) & 1u)) >> 16;
  return (short)r;
}

// ---------------- state init ----------------
__global__ __launch_bounds__(256)
void init_state_k(const float* __restrict__ h0, const float* __restrict__ c0,
                  float* __restrict__ hs, float* __restrict__ cs) {
  int i = blockIdx.x * 256 + threadIdx.x;
  hs[i] = h0[i];
  cs[i] = c0[i];
}

// ---------------- fp32 -> bf16 convert (4 elems/thread) ----------------
__global__ __launch_bounds__(256)
void cvt_f2b_k(const float* __restrict__ src, short* __restrict__ dst) {
  int i = (blockIdx.x * 256 + threadIdx.x) * 4;
  float4 v = *(const float4*)(src + i);
  short4 o;
  o.x = f2bf(v.x); o.y = f2bf(v.y); o.z = f2bf(v.z); o.w = f2bf(v.w);
  *(short4*)(dst + i) = o;
}

// ---------------- gather emb rows by dec, convert to bf16 ----------------
// 4096 rows x 512 cols, 4 elems/thread
__global__ __launch_bounds__(256)
void gather_emb_k(const int* __restrict__ dec, const float* __restrict__ emb,
                  short* __restrict__ XembB) {
  int idx = blockIdx.x * 256 + threadIdx.x;   // 524288 threads
  int r = idx >> 7, cc = (idx & 127) * 4;
  int src = dec[r];
  float4 v = *(const float4*)(emb + (size_t)src * ED + cc);
  short4 o;
  o.x = f2bf(v.x); o.y = f2bf(v.y); o.z = f2bf(v.z); o.w = f2bf(v.w);
  *(short4*)(XembB + (size_t)r * ED + cc) = o;
}

// ---------------- zero pad rows 4032..4095 of H1b ----------------
__global__ __launch_bounds__(256)
void pad_h1b_k(short* __restrict__ H1b) {
  int i = (blockIdx.x * 256 + threadIdx.x) * 4;  // 65536 shorts
  short4 z; z.x = z.y = z.z = z.w = 0;
  *(short4*)(H1b + (size_t)NROWS * HD + i) = z;
}

__global__ void zero_out_k(float* __restrict__ out) {
  if (threadIdx.x == 0) out[0] = 0.f;
}

// ---------------- shared MFMA K-loop: 128x128 tile, BK=64, 4 waves (2x2) ----
// A,B both K-major bf16 (row stride = lda/ldb shorts). LDS layout linear
// [128][64] with chunk16 XOR-swizzle applied via pre-swizzled global source.
template<int NK>
__device__ __forceinline__ void mfma_loop(const short* __restrict__ Abase, int lda,
                                          const short* __restrict__ Bbase, int ldb,
                                          short* lds_a, short* lds_b,
                                          f32x4 acc[4][4]) {
  const int tid = threadIdx.x;
  const int l = tid & 63;
  const int w = tid >> 6;
  const int wm = w >> 1, wn = w & 1;
  const int p = tid & 7;
  const int rbase = tid >> 3;

  for (int kt = 0; kt < NK; kt++) {
#pragma unroll
    for (int it = 0; it < 4; it++) {
      int row = it * 32 + rbase;
      int ch = p ^ (row & 7);                 // pre-swizzled source chunk
      const short* ga = Abase + (size_t)row * lda + kt * 64 + ch * 8;
      const short* gb = Bbase + (size_t)row * ldb + kt * 64 + ch * 8;
      short* la = lds_a + it * 2048 + tid * 8;  // linear dest (wave-uniform + lane*16)
      short* lb = lds_b + it * 2048 + tid * 8;
      __builtin_amdgcn_global_load_lds((const __attribute__((address_space(1))) void*)ga,
                                       (__attribute__((address_space(3))) void*)la, 16, 0, 0);
      __builtin_amdgcn_global_load_lds((const __attribute__((address_space(1))) void*)gb,
                                       (__attribute__((address_space(3))) void*)lb, 16, 0, 0);
    }
    asm volatile("s_waitcnt vmcnt(0)" ::: "memory");
    __syncthreads();

    short8 af[4][2], bf[4][2];
#pragma unroll
    for (int m = 0; m < 4; m++) {
#pragma unroll
      for (int ks = 0; ks < 2; ks++) {
        int ra = wm * 64 + m * 16 + (l & 15);
        int ca = (ks * 4 + (l >> 4)) ^ (ra & 7);   // swizzled read
        af[m][ks] = *(const short8*)(lds_a + ra * 64 + ca * 8);
        int rb = wn * 64 + m * 16 + (l & 15);
        int cb = (ks * 4 + (l >> 4)) ^ (rb & 7);
        bf[m][ks] = *(const short8*)(lds_b + rb * 64 + cb * 8);
      }
    }
#pragma unroll
    for (int ks = 0; ks < 2; ks++)
#pragma unroll
      for (int m = 0; m < 4; m++)
#pragma unroll
        for (int n = 0; n < 4; n++)
          acc[m][n] = __builtin_amdgcn_mfma_f32_16x16x32_bf16(af[m][ks], bf[n][ks],
                                                              acc[m][n], 0, 0, 0);
    __syncthreads();
  }
}

// ---------------- X0 = XembB @ Wih0B^T + bih0 + bhh0 (MFMA) ----------------
// grid (32, 32): rows(4096/128) x cols(4096/128)
__global__ __launch_bounds__(256)
void x0_mfma_k(const short* __restrict__ XembB, const short* __restrict__ Wih0B,
               const float* __restrict__ bih0, const float* __restrict__ bhh0,
               float* __restrict__ X0) {
  __shared__ short lds_a[128 * 64];
  __shared__ short lds_b[128 * 64];
  f32x4 acc[4][4];
#pragma unroll
  for (int m = 0; m < 4; m++)
#pragma unroll
    for (int n = 0; n < 4; n++)
#pragma unroll
      for (int q = 0; q < 4; q++) acc[m][n][q] = 0.f;

  mfma_loop<8>(XembB + (size_t)blockIdx.x * 128 * ED, ED,
               Wih0B + (size_t)blockIdx.y * 128 * ED, ED, lds_a, lds_b, acc);

  const int l = threadIdx.x & 63;
  const int w = threadIdx.x >> 6;
  const int wm = w >> 1, wn = w & 1;
#pragma unroll
  for (int m = 0; m < 4; m++)
#pragma unroll
    for (int r = 0; r < 4; r++) {
      int row = blockIdx.x * 128 + wm * 64 + m * 16 + (l >> 4) * 4 + r;
#pragma unroll
      for (int n = 0; n < 4; n++) {
        int col = blockIdx.y * 128 + wn * 64 + n * 16 + (l & 15);
        X0[(size_t)row * GG + col] = acc[m][n][r] + bih0[col] + bhh0[col];
      }
    }
}

// ---------------- fused logits MFMA GEMM + online LSE epilogue ----------------
// grid (32, 250): rowblocks x colblocks of 128. Writes m_part/s_part[ch][row],
// ch = blockIdx.y*2 + waveN (64-col chunks). Logits never materialized.
__global__ __launch_bounds__(256)
void lse_mfma_k(const short* __restrict__ H1b, const short* __restrict__ WoutB,
                const float* __restrict__ bout, float* __restrict__ m_part,
                float* __restrict__ s_part) {
  __shared__ short lds_a[128 * 64];
  __shared__ short lds_b[128 * 64];
  f32x4 acc[4][4];
#pragma unroll
  for (int m = 0; m < 4; m++)
#pragma unroll
    for (int n = 0; n < 4; n++)
#pragma unroll
      for (int q = 0; q < 4; q++) acc[m][n][q] = 0.f;

  mfma_loop<16>(H1b + (size_t)blockIdx.x * 128 * HD, HD,
                WoutB + (size_t)blockIdx.y * 128 * HD, HD, lds_a, lds_b, acc);

  const int l = threadIdx.x & 63;
  const int w = threadIdx.x >> 6;
  const int wm = w >> 1, wn = w & 1;
  const int colbase = blockIdx.y * 128 + wn * 64 + (l & 15);
  float bo[4];
#pragma unroll
  for (int n = 0; n < 4; n++) bo[n] = bout[colbase + n * 16];
  const int ch = blockIdx.y * 2 + wn;

#pragma unroll
  for (int m = 0; m < 4; m++) {
#pragma unroll
    for (int r = 0; r < 4; r++) {
      float v0 = acc[m][0][r] + bo[0];
      float v1 = acc[m][1][r] + bo[1];
      float v2 = acc[m][2][r] + bo[2];
      float v3 = acc[m][3][r] + bo[3];
      float mx = fmaxf(fmaxf(v0, v1), fmaxf(v2, v3));
      float s = __expf(v0 - mx) + __expf(v1 - mx) + __expf(v2 - mx) + __expf(v3 - mx);
#pragma unroll
      for (int off = 1; off < 16; off <<= 1) {
        float mo = __shfl_xor(mx, off);
        float so = __shfl_xor(s, off);
        float nm = fmaxf(mx, mo);
        s = s * __expf(mx - nm) + so * __expf(mo - nm);
        mx = nm;
      }
      if ((l & 15) == 0) {
        int row = blockIdx.x * 128 + wm * 64 + m * 16 + (l >> 4) * 4 + r;
        m_part[(size_t)ch * MPAD + row] = mx;
        s_part[(size_t)ch * MPAD + row] = s;
      }
    }
  }
}

// ---------------- recurrent partial GEMM (fp32, unchanged) ----------------
__global__ __launch_bounds__(256)
void rec_gemm_k(const float* __restrict__ A0, const float* __restrict__ W0,
                const float* __restrict__ A1, const float* __restrict__ W1,
                float* __restrict__ part) {
  __shared__ float As[16][68];
  __shared__ float Bs[16][68];
  int n0 = blockIdx.x * 64;
  int p  = blockIdx.y;
  const float* A = (p < 4) ? A0 : A1;
  const float* W = (p < 4) ? W0 : W1;
  int koff = (p & 3) * 256;
  int tid = threadIdx.x;
  int tx = tid & 15, ty = tid >> 4;
  int lm = tid >> 2, lk = (tid & 3) * 4;
  float acc[4][4] = {};
  for (int k0 = koff; k0 < koff + 256; k0 += 16) {
    float4 av = *(const float4*)(A + (size_t)lm * HD + k0 + lk);
    float4 bv = *(const float4*)(W + (size_t)(n0 + lm) * HD + k0 + lk);
    As[lk + 0][lm] = av.x; As[lk + 1][lm] = av.y; As[lk + 2][lm] = av.z; As[lk + 3][lm] = av.w;
    Bs[lk + 0][lm] = bv.x; Bs[lk + 1][lm] = bv.y; Bs[lk + 2][lm] = bv.z; Bs[lk + 3][lm] = bv.w;
    __syncthreads();
#pragma unroll
    for (int kk = 0; kk < 16; kk++) {
      float a4[4], b4[4];
      *(float4*)a4 = *(const float4*)&As[kk][ty * 4];
      *(float4*)b4 = *(const float4*)&Bs[kk][tx * 4];
#pragma unroll
      for (int i = 0; i < 4; i++)
#pragma unroll
        for (int j = 0; j < 4; j++) acc[i][j] += a4[i] * b4[j];
    }
    __syncthreads();
  }
  float* dst = part + (size_t)p * PSTRIDE;
#pragma unroll
  for (int i = 0; i < 4; i++)
#pragma unroll
    for (int j = 0; j < 4; j++)
      dst[(size_t)(ty * 4 + i) * GG + n0 + tx * 4 + j] = acc[i][j];
}

// ---------------- LSTM cell, layer 0 ----------------
__global__ __launch_bounds__(256)
void cell0_k(const float* __restrict__ X0t, const float* __restrict__ part,
             float* __restrict__ h, float* __restrict__ c) {
  int idx = blockIdx.x * 256 + threadIdx.x;
  int b = idx >> 10, j = idx & (HD - 1);
  float g[4];
#pragma unroll
  for (int q = 0; q < 4; q++) {
    size_t o = (size_t)b * GG + q * HD + j;
    g[q] = X0t[o] + part[o] + part[o + PSTRIDE] + part[o + 2 * PSTRIDE] + part[o + 3 * PSTRIDE];
  }
  float cn = sigf(g[1]) * c[idx] + sigf(g[0]) * tanhf(g[2]);
  float hn = sigf(g[3]) * tanhf(cn);
  c[idx] = cn;
  h[idx] = hn;
}

// ---------------- LSTM cell, layer 1 (writes H1 fp32 + H1b bf16) ----------------
__global__ __launch_bounds__(256)
void cell1_k(const float* __restrict__ part, const float* __restrict__ bih,
             const float* __restrict__ bhh, float* __restrict__ h,
             float* __restrict__ c, float* __restrict__ H1t,
             short* __restrict__ H1bt) {
  int idx = blockIdx.x * 256 + threadIdx.x;
  int b = idx >> 10, j = idx & (HD - 1);
  float g[4];
#pragma unroll
  for (int q = 0; q < 4; q++) {
    int gi = q * HD + j;
    size_t o = (size_t)b * GG + gi;
    float v = bih[gi] + bhh[gi];
#pragma unroll
    for (int p = 0; p < 8; p++) v += part[(size_t)p * PSTRIDE + o];
    g[q] = v;
  }
  float cn = sigf(g[1]) * c[idx] + sigf(g[0]) * tanhf(g[2]);
  float hn = sigf(g[3]) * tanhf(cn);
  c[idx] = cn;
  h[idx] = hn;
  H1t[idx] = hn;
  H1bt[idx] = f2bf(hn);
}

// ---------------- target logit (fp32 H1, exact) ----------------
__global__ __launch_bounds__(256)
void tgt_logit_k(const float* __restrict__ H1, const float* __restrict__ Wout,
                 const float* __restrict__ bout, const int* __restrict__ dec,
                 float* __restrict__ tl) {
  int gw = (blockIdx.x * 256 + threadIdx.x) >> 6;
  int lane = threadIdx.x & 63;
  if (gw >= NROWS) return;
  int tgt = dec[gw + 64];
  const float* hrow = H1 + (size_t)gw * HD;
  const float* wrow = Wout + (size_t)tgt * HD;
  float s = 0.f;
#pragma unroll
  for (int q = 0; q < 16; q++) {
    int k = lane + q * 64;
    s += hrow[k] * wrow[k];
  }
#pragma unroll
  for (int off = 32; off > 0; off >>= 1) s += __shfl_down(s, off);
  if (lane == 0) tl[gw] = s + bout[tgt];
}

// ---------------- per-row LSE merge over 500 chunks + loss atomicAdd --------
__global__ __launch_bounds__(256)
void row_lse_k(const float* __restrict__ m_part, const float* __restrict__ s_part,
               const float* __restrict__ tl, float* __restrict__ out) {
  int row = blockIdx.x * 256 + threadIdx.x;   // grid 16 -> 4096 threads
  float loss = 0.f;
  if (row < NROWS) {
    float M = -INFINITY, S = 0.f;
    for (int ch = 0; ch < NCH; ch++) {
      float m = m_part[(size_t)ch * MPAD + row];
      float s = s_part[(size_t)ch * MPAD + row];
      float nm = fmaxf(M, m);
      S = S * __expf(M - nm) + s * __expf(m - nm);
      M = nm;
    }
    loss = M + logf(S) - tl[row];
  }
  __shared__ float red[256];
  red[threadIdx.x] = loss;
  __syncthreads();
  for (int s = 128; s > 0; s >>= 1) {
    if (threadIdx.x < s) red[threadIdx.x] += red[threadIdx.x + s];
    __syncthreads();
  }
  if (threadIdx.x == 0) atomicAdd(out, red[0]);
}

extern "C" void kernel_launch(void* const* d_in, const int* in_sizes, int n_in,
                              void* d_out, int out_size, void* d_ws, size_t ws_size,
                              hipStream_t stream) {
  const int*   dec  = (const int*)  d_in[0];
  const float* h0   = (const float*)d_in[2];
  const float* c0   = (const float*)d_in[3];
  const float* emb  = (const float*)d_in[4];
  const float* Wih0 = (const float*)d_in[5];
  const float* Whh0 = (const float*)d_in[6];
  const float* bih0 = (const float*)d_in[7];
  const float* bhh0 = (const float*)d_in[8];
  const float* Wih1 = (const float*)d_in[9];
  const float* Whh1 = (const float*)d_in[10];
  const float* bih1 = (const float*)d_in[11];
  const float* bhh1 = (const float*)d_in[12];
  const float* Wout = (const float*)d_in[13];
  const float* bout = (const float*)d_in[14];
  float* out = (float*)d_out;

  float* ws = (float*)d_ws;
  float* X0     = ws;                                    // 4096*4096
  float* H1     = X0 + (size_t)MPAD * GG;                // 4032*1024
  float* hs     = H1 + (size_t)NROWS * HD;               // 2*64*1024
  float* cs     = hs + 2 * BB * HD;
  float* part   = cs + 2 * BB * HD;                      // 8*64*4096
  float* m_part = part + 8 * (size_t)BB * GG;            // 500*4096
  float* s_part = m_part + (size_t)NCH * MPAD;           // 500*4096
  float* tl     = s_part + (size_t)NCH * MPAD;           // 4096
  short* H1b    = (short*)(tl + MPAD);                   // 4096*1024 bf16
  short* WoutB  = H1b + (size_t)MPAD * HD;               // 32000*1024 bf16
  short* Wih0B  = WoutB + (size_t)VV * HD;               // 4096*512 bf16
  short* XembB  = Wih0B + (size_t)GG * ED;               // 4096*512 bf16
  // total ~192 MB of d_ws

  float* hs0 = hs, * hs1 = hs + BB * HD;
  float* cs0 = cs, * cs1 = cs + BB * HD;

  init_state_k<<<(2 * BB * HD) / 256, 256, 0, stream>>>(h0, c0, hs, cs);
  cvt_f2b_k<<<(VV * HD) / 1024, 256, 0, stream>>>(Wout, WoutB);
  cvt_f2b_k<<<(GG * ED) / 1024, 256, 0, stream>>>(Wih0, Wih0B);
  gather_emb_k<<<(MPAD * ED / 4) / 256, 256, 0, stream>>>(dec, emb, XembB);
  pad_h1b_k<<<64, 256, 0, stream>>>(H1b);
  zero_out_k<<<1, 64, 0, stream>>>(out);
  x0_mfma_k<<<dim3(MPAD / 128, GG / 128), 256, 0, stream>>>(XembB, Wih0B, bih0, bhh0, X0);

  for (int t = 0; t < TSTEPS; t++) {
    rec_gemm_k<<<dim3(64, 4), 256, 0, stream>>>(hs0, Whh0, hs0, Whh0, part);
    cell0_k<<<256, 256, 0, stream>>>(X0 + (size_t)t * BB * GG, part, hs0, cs0);
    rec_gemm_k<<<dim3(64, 8), 256, 0, stream>>>(hs0, Wih1, hs1, Whh1, part);
    cell1_k<<<256, 256, 0, stream>>>(part, bih1, bhh1, hs1, cs1,
                                     H1 + (size_t)t * BB * HD, H1b + (size_t)t * BB * HD);
  }

  tgt_logit_k<<<(NROWS * 64 + 255) / 256, 256, 0, stream>>>(H1, Wout, bout, dec, tl);
  lse_mfma_k<<<dim3(MPAD / 128, VV / 128), 256, 0, stream>>>(H1b, WoutB, bout, m_part, s_part);
  row_lse_k<<<MPAD / 256, 256, 0, stream>>>(m_part, s_part, tl, out);
}